// Round 1
// baseline (2052.863 us; speedup 1.0000x reference)
//
#include <hip/hip_runtime.h>
#include <hip/hip_bf16.h>
#include <cstddef>
#include <cstdint>

// ---------------------------------------------------------------------------
// Two-layer GCN, restructured: aggregate-then-GEMM (exact by linearity).
//   agg_l[d,:]  = sum_{e: dst_l[e]=d} X_l[src_l[e],:] * rsqrt(deg_out_l[src])
//   out_l[d,:]  = relu( (agg_l @ W_l) * rsqrt(deg_in_l[d]) + b_l )
// Shapes (fixed by setup_inputs): N_SRC0=400000, N_DST0=40000, N_DST1=4000,
// E0=400000, E1=40000, D=256 everywhere.
// ---------------------------------------------------------------------------

#define D 256
#define N_DST0_CONST 40000   // fixed by setup_inputs(); not derivable from in_sizes

// ---------------- zero ----------------
__global__ void zero_f(float* __restrict__ p, size_t n) {
    size_t i = (size_t)blockIdx.x * blockDim.x + threadIdx.x;
    size_t stride = (size_t)gridDim.x * blockDim.x;
    for (; i < n; i += stride) p[i] = 0.0f;
}

// ---------------- degree histogram ----------------
__global__ void count_deg(const int* __restrict__ src, const int* __restrict__ dst,
                          float* __restrict__ cnt_src, float* __restrict__ cnt_dst, int E) {
    int e = blockIdx.x * blockDim.x + threadIdx.x;
    if (e < E) {
        atomicAdd(&cnt_src[src[e]], 1.0f);
        atomicAdd(&cnt_dst[dst[e]], 1.0f);
    }
}

// counts -> rsqrt(max(count,1))
__global__ void finalize_rsqrt(float* __restrict__ p, int n) {
    int i = blockIdx.x * blockDim.x + threadIdx.x;
    if (i < n) p[i] = rsqrtf(fmaxf(p[i], 1.0f));
}

// ---------------- edge-parallel scatter aggregate ----------------
// blockDim = (64, 4): one wave per edge, lane handles float4 (64*4 = 256 = D).
__global__ __launch_bounds__(256) void scatter_agg(
    const float* __restrict__ X, const int* __restrict__ src, const int* __restrict__ dst,
    const float* __restrict__ rnorm_src, float* __restrict__ agg, int E) {
    int e = blockIdx.x * 4 + threadIdx.y;
    if (e >= E) return;
    int s = src[e];
    int d = dst[e];
    float sc = rnorm_src[s];
    int lane = threadIdx.x;
    float4 v = *(const float4*)(X + (size_t)s * D + lane * 4);
    float* ar = agg + (size_t)d * D + lane * 4;
    atomicAdd(ar + 0, v.x * sc);
    atomicAdd(ar + 1, v.y * sc);
    atomicAdd(ar + 2, v.z * sc);
    atomicAdd(ar + 3, v.w * sc);
}

// ---------------- fused GEMM * rsqrt(deg_in) + bias, relu ----------------
// out[m,n] = relu( rnorm[m] * sum_k A[m,k]*W[k,n] + bias[n] )
// 64x64 tile per block, 16x16 threads, 4x4 microtile, K staged in chunks of 16.
#define BM 64
#define BN 64
#define BK 16

__global__ __launch_bounds__(256) void gemm_scale_bias_relu(
    const float* __restrict__ A, const float* __restrict__ W,
    const float* __restrict__ rnorm, const float* __restrict__ bias,
    float* __restrict__ out, int M) {
    __shared__ float As[BM][BK + 1];
    __shared__ float Bs[BK][BN + 4];

    const int tx = threadIdx.x;   // 0..15
    const int ty = threadIdx.y;   // 0..15
    const int tid = ty * 16 + tx;
    const int m0 = blockIdx.x * BM;
    const int n0 = blockIdx.y * BN;

    // loader coordinates
    const int arow = tid >> 2;         // 0..63
    const int akg  = (tid & 3) * 4;    // 0,4,8,12
    const int bkk  = tid >> 4;         // 0..15
    const int bcg  = (tid & 15) * 4;   // 0..60

    float acc[4][4] = {};

    for (int k0 = 0; k0 < D; k0 += BK) {
        float4 av = make_float4(0.f, 0.f, 0.f, 0.f);
        int gm = m0 + arow;
        if (gm < M) av = *(const float4*)(A + (size_t)gm * D + k0 + akg);
        As[arow][akg + 0] = av.x;
        As[arow][akg + 1] = av.y;
        As[arow][akg + 2] = av.z;
        As[arow][akg + 3] = av.w;

        float4 bv = *(const float4*)(W + (size_t)(k0 + bkk) * D + n0 + bcg);
        *(float4*)(&Bs[bkk][bcg]) = bv;

        __syncthreads();

#pragma unroll
        for (int kk = 0; kk < BK; ++kk) {
            float a0 = As[ty * 4 + 0][kk];
            float a1 = As[ty * 4 + 1][kk];
            float a2 = As[ty * 4 + 2][kk];
            float a3 = As[ty * 4 + 3][kk];
            float b0 = Bs[kk][tx * 4 + 0];
            float b1 = Bs[kk][tx * 4 + 1];
            float b2 = Bs[kk][tx * 4 + 2];
            float b3 = Bs[kk][tx * 4 + 3];
            acc[0][0] += a0 * b0; acc[0][1] += a0 * b1; acc[0][2] += a0 * b2; acc[0][3] += a0 * b3;
            acc[1][0] += a1 * b0; acc[1][1] += a1 * b1; acc[1][2] += a1 * b2; acc[1][3] += a1 * b3;
            acc[2][0] += a2 * b0; acc[2][1] += a2 * b1; acc[2][2] += a2 * b2; acc[2][3] += a2 * b3;
            acc[3][0] += a3 * b0; acc[3][1] += a3 * b1; acc[3][2] += a3 * b2; acc[3][3] += a3 * b3;
        }
        __syncthreads();
    }

#pragma unroll
    for (int i = 0; i < 4; ++i) {
        int gm = m0 + ty * 4 + i;
        if (gm >= M) continue;
        float sc = rnorm[gm];
        float4 o;
        int gn = n0 + tx * 4;
        o.x = fmaxf(acc[i][0] * sc + bias[gn + 0], 0.f);
        o.y = fmaxf(acc[i][1] * sc + bias[gn + 1], 0.f);
        o.z = fmaxf(acc[i][2] * sc + bias[gn + 2], 0.f);
        o.w = fmaxf(acc[i][3] * sc + bias[gn + 3], 0.f);
        *(float4*)(out + (size_t)gm * D + gn) = o;
    }
}

// ---------------------------------------------------------------------------

extern "C" void kernel_launch(void* const* d_in, const int* in_sizes, int n_in,
                              void* d_out, int out_size, void* d_ws, size_t ws_size,
                              hipStream_t stream) {
    const float* x    = (const float*)d_in[0];
    const int*   src0 = (const int*)d_in[1];
    const int*   dst0 = (const int*)d_in[2];
    const int*   src1 = (const int*)d_in[3];
    const int*   dst1 = (const int*)d_in[4];
    const float* W0   = (const float*)d_in[5];
    const float* b0   = (const float*)d_in[6];
    const float* W1   = (const float*)d_in[7];
    const float* b1   = (const float*)d_in[8];

    const int n_src0 = in_sizes[0] / D;      // 400000
    const int E0     = in_sizes[1];          // 400000
    const int E1     = in_sizes[3];          // 40000
    const int n_dst0 = N_DST0_CONST;         // 40000
    const int n_dst1 = out_size / D;         // 4000

    float* ws = (float*)d_ws;
    // ws layout (floats)
    size_t off = 0;
    float* cnt_src0 = ws + off; off += n_src0;            // 400000
    float* cnt_dst0 = ws + off; off += n_dst0;            // 40000
    float* cnt_src1 = ws + off; off += n_dst0;            // 40000 (src of layer1 ranges over n_dst0)
    float* cnt_dst1 = ws + off; off += n_dst1;            // 4000
    const size_t cnt_total = off;                         // 484000
    float* agg0 = ws + off; off += (size_t)n_dst0 * D;    // 10.24M
    float* h0   = ws + off; off += (size_t)n_dst0 * D;    // 10.24M
    float* agg1 = ws + off; off += (size_t)n_dst1 * D;    // 1.024M
    const size_t zero_total = off;                        // h0 included (cheap, simpler)

    float* out = (float*)d_out;

    // 1. zero counts + agg buffers (ws is poisoned 0xAA before every call)
    {
        int blocks = 4096;
        zero_f<<<blocks, 256, 0, stream>>>(ws, zero_total);
    }

    // 2. degree histograms
    count_deg<<<(E0 + 255) / 256, 256, 0, stream>>>(src0, dst0, cnt_src0, cnt_dst0, E0);
    count_deg<<<(E1 + 255) / 256, 256, 0, stream>>>(src1, dst1, cnt_src1, cnt_dst1, E1);

    // 3. counts -> rsqrt(clip(count,1))
    finalize_rsqrt<<<(int)((cnt_total + 255) / 256), 256, 0, stream>>>(ws, (int)cnt_total);

    // 4. layer0 scatter-aggregate: agg0[d] += x[s]*rsqrt(deg_out0[s])
    {
        dim3 blk(64, 4);
        scatter_agg<<<(E0 + 3) / 4, blk, 0, stream>>>(x, src0, dst0, cnt_src0, agg0, E0);
    }

    // 5. layer0 GEMM + post-norm + bias + relu -> h0
    {
        dim3 grid((n_dst0 + BM - 1) / BM, D / BN);
        dim3 blk(16, 16);
        gemm_scale_bias_relu<<<grid, blk, 0, stream>>>(agg0, W0, cnt_dst0, b0, h0, n_dst0);
    }

    // 6. layer1 scatter-aggregate: agg1[d] += h0[s]*rsqrt(deg_out1[s])
    {
        dim3 blk(64, 4);
        scatter_agg<<<(E1 + 3) / 4, blk, 0, stream>>>(h0, src1, dst1, cnt_src1, agg1, E1);
    }

    // 7. layer1 GEMM + post-norm + bias + relu -> d_out
    {
        dim3 grid((n_dst1 + BM - 1) / BM, D / BN);
        dim3 blk(16, 16);
        gemm_scale_bias_relu<<<grid, blk, 0, stream>>>(agg1, W1, cnt_dst1, b1, out, n_dst1);
    }
}

// Round 2
// 791.582 us; speedup vs baseline: 2.5934x; 2.5934x over previous
//
#include <hip/hip_runtime.h>
#include <hip/hip_bf16.h>
#include <cstddef>
#include <cstdint>

// ---------------------------------------------------------------------------
// Two-layer GCN, aggregate-then-GEMM (exact by linearity), CSR gather (R2):
//   agg_l[d,:]  = sum_{e: dst_l[e]=d} X_l[src_l[e],:] * rsqrt(deg_out_l[src])
//   out_l[d,:]  = relu( (agg_l @ W_l) * rsqrt(deg_in_l[d]) + b_l )
// R1 used per-edge float atomics: 1.6 GB WRITE_SIZE (4x amplification),
// 1332 us. R2 buckets edges by dst on device (histogram + scan + fill),
// then gathers per-dst-row with register accumulation -> one row write.
// ---------------------------------------------------------------------------

#define D 256
#define N_DST0_CONST 40000   // fixed by setup_inputs(); not derivable from in_sizes

// ---------------- zero (ints) ----------------
__global__ void zero_i(int* __restrict__ p, int n) {
    int i = blockIdx.x * blockDim.x + threadIdx.x;
    int stride = gridDim.x * blockDim.x;
    for (; i < n; i += stride) p[i] = 0;
}

// ---------------- degree histogram (int) ----------------
__global__ void count_deg(const int* __restrict__ src, const int* __restrict__ dst,
                          int* __restrict__ cnt_src, int* __restrict__ cnt_dst, int E) {
    int e = blockIdx.x * blockDim.x + threadIdx.x;
    if (e < E) {
        atomicAdd(&cnt_src[src[e]], 1);
        atomicAdd(&cnt_dst[dst[e]], 1);
    }
}

// int counts -> float rsqrt(max(count,1)); counts preserved for the scan
__global__ void finalize_rsqrt(const int* __restrict__ cnt, float* __restrict__ rnorm, int n) {
    int i = blockIdx.x * blockDim.x + threadIdx.x;
    if (i < n) rnorm[i] = rsqrtf(fmaxf((float)cnt[i], 1.0f));
}

// ---------------- single-block exclusive scan ----------------
// n up to ~40000; 1024 threads, each scans a contiguous chunk.
__global__ __launch_bounds__(1024) void ex_scan(const int* __restrict__ cnt,
                                                int* __restrict__ ptr, int n) {
    __shared__ int wsum[16];
    const int tid = threadIdx.x;
    const int chunk = (n + 1023) / 1024;
    const int begin = tid * chunk;
    const int end = min(begin + chunk, n);
    int local = 0;
    for (int i = begin; i < end; ++i) local += cnt[i];
    // wave-inclusive scan of `local`
    const int lane = tid & 63;
    const int wid = tid >> 6;
    int v = local;
    for (int off = 1; off < 64; off <<= 1) {
        int u = __shfl_up(v, off, 64);
        if (lane >= off) v += u;
    }
    if (lane == 63) wsum[wid] = v;
    __syncthreads();
    if (wid == 0 && lane < 16) {
        int w = wsum[lane];
        for (int off = 1; off < 16; off <<= 1) {
            int u = __shfl_up(w, off, 16);
            if (lane >= off) w += u;
        }
        wsum[lane] = w;
    }
    __syncthreads();
    int base = (wid > 0 ? wsum[wid - 1] : 0) + (v - local);  // exclusive prefix for this thread
    int run = base;
    for (int i = begin; i < end; ++i) { ptr[i] = run; run += cnt[i]; }
}

// ---------------- CSR fill ----------------
// Uses ptr itself as the running cursor: after this kernel, ptr[d] == original
// exclusive prefix of d+1, so row d's range is [d==0?0:ptr[d-1], ptr[d]).
__global__ void fill_csr(const int* __restrict__ src, const int* __restrict__ dst,
                         int* __restrict__ ptr, int* __restrict__ edge_src, int E) {
    int e = blockIdx.x * blockDim.x + threadIdx.x;
    if (e < E) {
        int pos = atomicAdd(&ptr[dst[e]], 1);
        edge_src[pos] = src[e];
    }
}

// ---------------- CSR gather aggregate ----------------
// blockDim = (64,4): one wave per dst row; lane handles float4 (64*4=256=D).
// Register accumulation, single row write, no atomics.
__global__ __launch_bounds__(256) void gather_agg(
    const float* __restrict__ X, const int* __restrict__ edge_src,
    const int* __restrict__ ptr, const float* __restrict__ rnorm_src,
    float* __restrict__ agg, int nrows) {
    int d = blockIdx.x * 4 + threadIdx.y;
    if (d >= nrows) return;
    int beg = (d == 0) ? 0 : ptr[d - 1];
    int end = ptr[d];
    int lane = threadIdx.x;
    float4 acc = make_float4(0.f, 0.f, 0.f, 0.f);
    for (int j = beg; j < end; ++j) {
        int s = edge_src[j];               // uniform across wave, cache-broadcast
        float sc = rnorm_src[s];
        float4 v = *(const float4*)(X + (size_t)s * D + lane * 4);
        acc.x += v.x * sc;
        acc.y += v.y * sc;
        acc.z += v.z * sc;
        acc.w += v.w * sc;
    }
    *(float4*)(agg + (size_t)d * D + lane * 4) = acc;
}

// ---------------- fused GEMM * rsqrt(deg_in) + bias, relu ----------------
// out[m,n] = relu( rnorm[m] * sum_k A[m,k]*W[k,n] + bias[n] )
#define BM 64
#define BN 64
#define BK 16

__global__ __launch_bounds__(256) void gemm_scale_bias_relu(
    const float* __restrict__ A, const float* __restrict__ W,
    const float* __restrict__ rnorm, const float* __restrict__ bias,
    float* __restrict__ out, int M) {
    __shared__ float As[BM][BK + 1];
    __shared__ float Bs[BK][BN + 4];

    const int tx = threadIdx.x;   // 0..15
    const int ty = threadIdx.y;   // 0..15
    const int tid = ty * 16 + tx;
    const int m0 = blockIdx.x * BM;
    const int n0 = blockIdx.y * BN;

    const int arow = tid >> 2;
    const int akg  = (tid & 3) * 4;
    const int bkk  = tid >> 4;
    const int bcg  = (tid & 15) * 4;

    float acc[4][4] = {};

    for (int k0 = 0; k0 < D; k0 += BK) {
        float4 av = make_float4(0.f, 0.f, 0.f, 0.f);
        int gm = m0 + arow;
        if (gm < M) av = *(const float4*)(A + (size_t)gm * D + k0 + akg);
        As[arow][akg + 0] = av.x;
        As[arow][akg + 1] = av.y;
        As[arow][akg + 2] = av.z;
        As[arow][akg + 3] = av.w;

        float4 bv = *(const float4*)(W + (size_t)(k0 + bkk) * D + n0 + bcg);
        *(float4*)(&Bs[bkk][bcg]) = bv;

        __syncthreads();

#pragma unroll
        for (int kk = 0; kk < BK; ++kk) {
            float a0 = As[ty * 4 + 0][kk];
            float a1 = As[ty * 4 + 1][kk];
            float a2 = As[ty * 4 + 2][kk];
            float a3 = As[ty * 4 + 3][kk];
            float b0 = Bs[kk][tx * 4 + 0];
            float b1 = Bs[kk][tx * 4 + 1];
            float b2 = Bs[kk][tx * 4 + 2];
            float b3 = Bs[kk][tx * 4 + 3];
            acc[0][0] += a0 * b0; acc[0][1] += a0 * b1; acc[0][2] += a0 * b2; acc[0][3] += a0 * b3;
            acc[1][0] += a1 * b0; acc[1][1] += a1 * b1; acc[1][2] += a1 * b2; acc[1][3] += a1 * b3;
            acc[2][0] += a2 * b0; acc[2][1] += a2 * b1; acc[2][2] += a2 * b2; acc[2][3] += a2 * b3;
            acc[3][0] += a3 * b0; acc[3][1] += a3 * b1; acc[3][2] += a3 * b2; acc[3][3] += a3 * b3;
        }
        __syncthreads();
    }

#pragma unroll
    for (int i = 0; i < 4; ++i) {
        int gm = m0 + ty * 4 + i;
        if (gm >= M) continue;
        float sc = rnorm[gm];
        float4 o;
        int gn = n0 + tx * 4;
        o.x = fmaxf(acc[i][0] * sc + bias[gn + 0], 0.f);
        o.y = fmaxf(acc[i][1] * sc + bias[gn + 1], 0.f);
        o.z = fmaxf(acc[i][2] * sc + bias[gn + 2], 0.f);
        o.w = fmaxf(acc[i][3] * sc + bias[gn + 3], 0.f);
        *(float4*)(out + (size_t)gm * D + gn) = o;
    }
}

// ---------------------------------------------------------------------------

extern "C" void kernel_launch(void* const* d_in, const int* in_sizes, int n_in,
                              void* d_out, int out_size, void* d_ws, size_t ws_size,
                              hipStream_t stream) {
    const float* x    = (const float*)d_in[0];
    const int*   src0 = (const int*)d_in[1];
    const int*   dst0 = (const int*)d_in[2];
    const int*   src1 = (const int*)d_in[3];
    const int*   dst1 = (const int*)d_in[4];
    const float* W0   = (const float*)d_in[5];
    const float* b0   = (const float*)d_in[6];
    const float* W1   = (const float*)d_in[7];
    const float* b1   = (const float*)d_in[8];

    const int n_src0 = in_sizes[0] / D;      // 400000
    const int E0     = in_sizes[1];          // 400000
    const int E1     = in_sizes[3];          // 40000
    const int n_dst0 = N_DST0_CONST;         // 40000
    const int n_dst1 = out_size / D;         // 4000

    // ---- workspace layout ----
    int* wi = (int*)d_ws;
    size_t ioff = 0;
    int* icnt_src0 = wi + ioff; ioff += n_src0;   // 400000  } contiguous: zeroed
    int* icnt_dst0 = wi + ioff; ioff += n_dst0;   //  40000  } and rsqrt'd as
    int* icnt_src1 = wi + ioff; ioff += n_dst0;   //  40000  } one region
    int* icnt_dst1 = wi + ioff; ioff += n_dst1;   //   4000  }
    const int cnt_total = (int)ioff;              // 484000
    int* ptr0      = wi + ioff; ioff += n_dst0;
    int* ptr1      = wi + ioff; ioff += n_dst1;
    int* edge_src0 = wi + ioff; ioff += E0;
    int* edge_src1 = wi + ioff; ioff += E1;

    float* wf = (float*)d_ws + ioff;
    size_t foff = 0;
    float* rnorm = wf + foff; foff += cnt_total;  // parallel to icnt_* region
    float* rnorm_src0 = rnorm;
    float* rnorm_dst0 = rnorm + n_src0;
    float* rnorm_src1 = rnorm + n_src0 + n_dst0;
    float* rnorm_dst1 = rnorm + n_src0 + 2 * (size_t)n_dst0;
    float* agg0 = wf + foff; foff += (size_t)n_dst0 * D;
    float* h0   = wf + foff; foff += (size_t)n_dst0 * D;
    float* agg1 = wf + foff; foff += (size_t)n_dst1 * D;

    float* out = (float*)d_out;

    // 1. zero the count region (ws is poisoned 0xAA before every call)
    zero_i<<<512, 256, 0, stream>>>(wi, cnt_total);

    // 2. degree histograms
    count_deg<<<(E0 + 255) / 256, 256, 0, stream>>>(src0, dst0, icnt_src0, icnt_dst0, E0);
    count_deg<<<(E1 + 255) / 256, 256, 0, stream>>>(src1, dst1, icnt_src1, icnt_dst1, E1);

    // 3. counts -> rsqrt(clip(count,1)) (counts preserved)
    finalize_rsqrt<<<(cnt_total + 255) / 256, 256, 0, stream>>>(wi, rnorm, cnt_total);

    // 4. exclusive scans (dst counts -> CSR row ptrs)
    ex_scan<<<1, 1024, 0, stream>>>(icnt_dst0, ptr0, n_dst0);
    ex_scan<<<1, 1024, 0, stream>>>(icnt_dst1, ptr1, n_dst1);

    // 5. CSR fill (ptr becomes inclusive end-offsets)
    fill_csr<<<(E0 + 255) / 256, 256, 0, stream>>>(src0, dst0, ptr0, edge_src0, E0);
    fill_csr<<<(E1 + 255) / 256, 256, 0, stream>>>(src1, dst1, ptr1, edge_src1, E1);

    // 6. layer0: gather-aggregate then GEMM+post-norm+bias+relu
    {
        dim3 blk(64, 4);
        gather_agg<<<(n_dst0 + 3) / 4, blk, 0, stream>>>(x, edge_src0, ptr0, rnorm_src0, agg0, n_dst0);
        dim3 grid((n_dst0 + BM - 1) / BM, D / BN);
        dim3 tb(16, 16);
        gemm_scale_bias_relu<<<grid, tb, 0, stream>>>(agg0, W0, rnorm_dst0, b0, h0, n_dst0);
    }

    // 7. layer1: gather-aggregate then GEMM+post-norm+bias+relu -> d_out
    {
        dim3 blk(64, 4);
        gather_agg<<<(n_dst1 + 3) / 4, blk, 0, stream>>>(h0, edge_src1, ptr1, rnorm_src1, agg1, n_dst1);
        dim3 grid((n_dst1 + BM - 1) / BM, D / BN);
        dim3 tb(16, 16);
        gemm_scale_bias_relu<<<grid, tb, 0, stream>>>(agg1, W1, rnorm_dst1, b1, out, n_dst1);
    }
}

// Round 3
// 728.555 us; speedup vs baseline: 2.8177x; 1.0865x over previous
//
#include <hip/hip_runtime.h>
#include <hip/hip_bf16.h>
#include <cstddef>
#include <cstdint>

// ---------------------------------------------------------------------------
// Two-layer GCN, aggregate-then-GEMM (exact by linearity), CSR gather (R2),
// bf16 MFMA GEMM (R3):
//   agg_l[d,:]  = sum_{e: dst_l[e]=d} X_l[src_l[e],:] * rsqrt(deg_out_l[src])
//   out_l[d,:]  = relu( (agg_l @ W_l) * rsqrt(deg_in_l[d]) + b_l )
// R3: gather writes bf16 agg; GEMM = 128x128 tile, 4 waves, 16x16x32 bf16
// MFMA with W^T staged bf16; fused scale+bias+relu epilogue.
// ---------------------------------------------------------------------------

#define D 256
#define N_DST0_CONST 40000   // fixed by setup_inputs(); not derivable from in_sizes

typedef __attribute__((ext_vector_type(8))) short s16x8;   // bf16 x8 (4 VGPRs)
typedef __attribute__((ext_vector_type(4))) short s16x4;   // bf16 x4
typedef __attribute__((ext_vector_type(4))) float f32x4;   // fp32 x4 acc

__device__ inline short f2bf(float f) {
    __hip_bfloat16 h = __float2bfloat16(f);
    return *reinterpret_cast<short*>(&h);
}

// ---------------- zero (ints) ----------------
__global__ void zero_i(int* __restrict__ p, int n) {
    int i = blockIdx.x * blockDim.x + threadIdx.x;
    int stride = gridDim.x * blockDim.x;
    for (; i < n; i += stride) p[i] = 0;
}

// ---------------- degree histogram (int) ----------------
__global__ void count_deg(const int* __restrict__ src, const int* __restrict__ dst,
                          int* __restrict__ cnt_src, int* __restrict__ cnt_dst, int E) {
    int e = blockIdx.x * blockDim.x + threadIdx.x;
    if (e < E) {
        atomicAdd(&cnt_src[src[e]], 1);
        atomicAdd(&cnt_dst[dst[e]], 1);
    }
}

// int counts -> float rsqrt(max(count,1)); counts preserved for the scan
__global__ void finalize_rsqrt(const int* __restrict__ cnt, float* __restrict__ rnorm, int n) {
    int i = blockIdx.x * blockDim.x + threadIdx.x;
    if (i < n) rnorm[i] = rsqrtf(fmaxf((float)cnt[i], 1.0f));
}

// ---------------- single-block exclusive scan ----------------
__global__ __launch_bounds__(1024) void ex_scan(const int* __restrict__ cnt,
                                                int* __restrict__ ptr, int n) {
    __shared__ int wsum[16];
    const int tid = threadIdx.x;
    const int chunk = (n + 1023) / 1024;
    const int begin = tid * chunk;
    const int end = min(begin + chunk, n);
    int local = 0;
    for (int i = begin; i < end; ++i) local += cnt[i];
    const int lane = tid & 63;
    const int wid = tid >> 6;
    int v = local;
    for (int off = 1; off < 64; off <<= 1) {
        int u = __shfl_up(v, off, 64);
        if (lane >= off) v += u;
    }
    if (lane == 63) wsum[wid] = v;
    __syncthreads();
    if (wid == 0 && lane < 16) {
        int w = wsum[lane];
        for (int off = 1; off < 16; off <<= 1) {
            int u = __shfl_up(w, off, 16);
            if (lane >= off) w += u;
        }
        wsum[lane] = w;
    }
    __syncthreads();
    int base = (wid > 0 ? wsum[wid - 1] : 0) + (v - local);
    int run = base;
    for (int i = begin; i < end; ++i) { ptr[i] = run; run += cnt[i]; }
}

// ---------------- CSR fill ----------------
// After this kernel ptr[d] == exclusive prefix of d+1: row d = [ptr[d-1], ptr[d]).
__global__ void fill_csr(const int* __restrict__ src, const int* __restrict__ dst,
                         int* __restrict__ ptr, int* __restrict__ edge_src, int E) {
    int e = blockIdx.x * blockDim.x + threadIdx.x;
    if (e < E) {
        int pos = atomicAdd(&ptr[dst[e]], 1);
        edge_src[pos] = src[e];
    }
}

// ---------------- CSR gather aggregate -> bf16 ----------------
// blockDim = (64,4): one wave per dst row; lane handles 4 cols (fp32 acc).
__global__ __launch_bounds__(256) void gather_agg_bf16(
    const float* __restrict__ X, const int* __restrict__ edge_src,
    const int* __restrict__ ptr, const float* __restrict__ rnorm_src,
    short* __restrict__ agg, int nrows) {
    int d = blockIdx.x * 4 + threadIdx.y;
    if (d >= nrows) return;
    int beg = (d == 0) ? 0 : ptr[d - 1];
    int end = ptr[d];
    int lane = threadIdx.x;
    float4 acc = make_float4(0.f, 0.f, 0.f, 0.f);
    for (int j = beg; j < end; ++j) {
        int s = edge_src[j];               // wave-uniform, cache-broadcast
        float sc = rnorm_src[s];
        float4 v = *(const float4*)(X + (size_t)s * D + lane * 4);
        acc.x += v.x * sc;
        acc.y += v.y * sc;
        acc.z += v.z * sc;
        acc.w += v.w * sc;
    }
    s16x4 o;
    o.x = f2bf(acc.x); o.y = f2bf(acc.y); o.z = f2bf(acc.z); o.w = f2bf(acc.w);
    *(s16x4*)(agg + (size_t)d * D + lane * 4) = o;
}

// ---------------- W (KxN fp32) -> W^T (NxK bf16) ----------------
__global__ __launch_bounds__(256) void transpose_cast_w(const float* __restrict__ W,
                                                        short* __restrict__ BT) {
    __shared__ float t[16][17];
    int k0 = blockIdx.x * 16, n0 = blockIdx.y * 16;
    t[threadIdx.y][threadIdx.x] = W[(size_t)(k0 + threadIdx.y) * D + n0 + threadIdx.x];
    __syncthreads();
    BT[(size_t)(n0 + threadIdx.y) * D + k0 + threadIdx.x] = f2bf(t[threadIdx.x][threadIdx.y]);
}

// ---------------- bf16 MFMA GEMM: out = relu(rnorm[m]*(A@W) + bias) ----------------
// A [M][256] bf16, BT [256][256] bf16 (BT[n][k] = W[k][n]), out [M][256] fp32.
// 128x128 tile / block, 4 waves (2x2), each wave 64x64 via 4x4 16x16x32 MFMAs.
#define LDK 40   // padded LDS k-stride (bf16 elems): 80B rows -> 2-way bank aliasing (free)

__global__ __launch_bounds__(256) void gemm_bf16_mfma(
    const short* __restrict__ A, const short* __restrict__ BT,
    const float* __restrict__ rnorm, const float* __restrict__ bias,
    float* __restrict__ out, int M) {
    __shared__ short As[128][LDK];
    __shared__ short Bs[128][LDK];

    const int tid = threadIdx.x;           // 0..255
    const int m0 = blockIdx.x * 128;
    const int n0 = blockIdx.y * 128;
    const int wave = tid >> 6;             // 0..3
    const int lane = tid & 63;
    const int l15 = lane & 15;
    const int quad = lane >> 4;
    const int mo = (wave & 1) * 64;        // wave tile origin within block tile
    const int no = (wave >> 1) * 64;

    f32x4 acc[4][4] = {};

    for (int k0 = 0; k0 < D; k0 += 32) {
        // stage A/B tiles: 128 rows x 32 k each; 512 x 16B loads = 2 per thread each
#pragma unroll
        for (int i = 0; i < 2; ++i) {
            int idx = tid + i * 256;
            int row = idx >> 2;
            int kg = (idx & 3) * 8;
            int gm = m0 + row;
            s16x8 av = {};
            if (gm < M) av = *(const s16x8*)(A + (size_t)gm * D + k0 + kg);
            *(s16x8*)&As[row][kg] = av;
            s16x8 bv = *(const s16x8*)(BT + (size_t)(n0 + row) * D + k0 + kg);
            *(s16x8*)&Bs[row][kg] = bv;
        }
        __syncthreads();

        s16x8 af[4], bf[4];
#pragma unroll
        for (int mt = 0; mt < 4; ++mt)
            af[mt] = *(const s16x8*)&As[mo + mt * 16 + l15][quad * 8];
#pragma unroll
        for (int nt = 0; nt < 4; ++nt)
            bf[nt] = *(const s16x8*)&Bs[no + nt * 16 + l15][quad * 8];
#pragma unroll
        for (int mt = 0; mt < 4; ++mt)
#pragma unroll
            for (int nt = 0; nt < 4; ++nt)
                acc[mt][nt] = __builtin_amdgcn_mfma_f32_16x16x32_bf16(
                    af[mt], bf[nt], acc[mt][nt], 0, 0, 0);
        __syncthreads();
    }

    // epilogue: D row = quad*4 + r, col = l15 (per 16x16 tile)
#pragma unroll
    for (int mt = 0; mt < 4; ++mt) {
#pragma unroll
        for (int r = 0; r < 4; ++r) {
            int gm = m0 + mo + mt * 16 + quad * 4 + r;
            if (gm >= M) continue;
            float sc = rnorm[gm];
#pragma unroll
            for (int nt = 0; nt < 4; ++nt) {
                int gn = n0 + no + nt * 16 + l15;
                float v = fmaxf(acc[mt][nt][r] * sc + bias[gn], 0.f);
                out[(size_t)gm * D + gn] = v;
            }
        }
    }
}

// ---------------------------------------------------------------------------

extern "C" void kernel_launch(void* const* d_in, const int* in_sizes, int n_in,
                              void* d_out, int out_size, void* d_ws, size_t ws_size,
                              hipStream_t stream) {
    const float* x    = (const float*)d_in[0];
    const int*   src0 = (const int*)d_in[1];
    const int*   dst0 = (const int*)d_in[2];
    const int*   src1 = (const int*)d_in[3];
    const int*   dst1 = (const int*)d_in[4];
    const float* W0   = (const float*)d_in[5];
    const float* b0   = (const float*)d_in[6];
    const float* W1   = (const float*)d_in[7];
    const float* b1   = (const float*)d_in[8];

    const int n_src0 = in_sizes[0] / D;      // 400000
    const int E0     = in_sizes[1];          // 400000
    const int E1     = in_sizes[3];          // 40000
    const int n_dst0 = N_DST0_CONST;         // 40000
    const int n_dst1 = out_size / D;         // 4000

    // ---- workspace layout (byte-offset based, 64B-aligned regions) ----
    char* base = (char*)d_ws;
    size_t off = 0;
    auto alloc = [&](size_t bytes) { void* p = base + off; off = (off + bytes + 63) & ~(size_t)63; return p; };

    int* icnt = (int*)alloc((size_t)(n_src0 + 2 * n_dst0 + n_dst1) * 4);
    int* icnt_src0 = icnt;
    int* icnt_dst0 = icnt + n_src0;
    int* icnt_src1 = icnt + n_src0 + n_dst0;
    int* icnt_dst1 = icnt + n_src0 + 2 * n_dst0;
    const int cnt_total = n_src0 + 2 * n_dst0 + n_dst1;    // 484000

    int* ptr0      = (int*)alloc((size_t)n_dst0 * 4);
    int* ptr1      = (int*)alloc((size_t)n_dst1 * 4);
    int* edge_src0 = (int*)alloc((size_t)E0 * 4);
    int* edge_src1 = (int*)alloc((size_t)E1 * 4);

    float* rnorm = (float*)alloc((size_t)cnt_total * 4);
    float* rnorm_src0 = rnorm;
    float* rnorm_dst0 = rnorm + n_src0;
    float* rnorm_src1 = rnorm + n_src0 + n_dst0;
    float* rnorm_dst1 = rnorm + n_src0 + 2 * (size_t)n_dst0;

    float* h0    = (float*)alloc((size_t)n_dst0 * D * 4);
    short* aggb0 = (short*)alloc((size_t)n_dst0 * D * 2);
    short* aggb1 = (short*)alloc((size_t)n_dst1 * D * 2);
    short* BT0   = (short*)alloc((size_t)D * D * 2);
    short* BT1   = (short*)alloc((size_t)D * D * 2);

    float* out = (float*)d_out;

    // 1. zero the count region
    zero_i<<<512, 256, 0, stream>>>(icnt, cnt_total);

    // 2. degree histograms
    count_deg<<<(E0 + 255) / 256, 256, 0, stream>>>(src0, dst0, icnt_src0, icnt_dst0, E0);
    count_deg<<<(E1 + 255) / 256, 256, 0, stream>>>(src1, dst1, icnt_src1, icnt_dst1, E1);

    // 3. counts -> rsqrt(clip(count,1))
    finalize_rsqrt<<<(cnt_total + 255) / 256, 256, 0, stream>>>(icnt, rnorm, cnt_total);

    // 4. exclusive scans
    ex_scan<<<1, 1024, 0, stream>>>(icnt_dst0, ptr0, n_dst0);
    ex_scan<<<1, 1024, 0, stream>>>(icnt_dst1, ptr1, n_dst1);

    // 5. CSR fill
    fill_csr<<<(E0 + 255) / 256, 256, 0, stream>>>(src0, dst0, ptr0, edge_src0, E0);
    fill_csr<<<(E1 + 255) / 256, 256, 0, stream>>>(src1, dst1, ptr1, edge_src1, E1);

    // 5b. W -> W^T bf16
    {
        dim3 g(D / 16, D / 16), b(16, 16);
        transpose_cast_w<<<g, b, 0, stream>>>(W0, BT0);
        transpose_cast_w<<<g, b, 0, stream>>>(W1, BT1);
    }

    // 6. layer0
    {
        dim3 blk(64, 4);
        gather_agg_bf16<<<(n_dst0 + 3) / 4, blk, 0, stream>>>(x, edge_src0, ptr0, rnorm_src0, aggb0, n_dst0);
        dim3 grid((n_dst0 + 127) / 128, D / 128);
        gemm_bf16_mfma<<<grid, 256, 0, stream>>>(aggb0, BT0, rnorm_dst0, b0, h0, n_dst0);
    }

    // 7. layer1 -> d_out
    {
        dim3 blk(64, 4);
        gather_agg_bf16<<<(n_dst1 + 3) / 4, blk, 0, stream>>>(h0, edge_src1, ptr1, rnorm_src1, aggb1, n_dst1);
        dim3 grid((n_dst1 + 127) / 128, D / 128);
        gemm_bf16_mfma<<<grid, 256, 0, stream>>>(aggb1, BT1, rnorm_dst1, b1, out, n_dst1);
    }
}

// Round 4
// 697.090 us; speedup vs baseline: 2.9449x; 1.0451x over previous
//
#include <hip/hip_runtime.h>
#include <hip/hip_bf16.h>
#include <cstddef>
#include <cstdint>

// ---------------------------------------------------------------------------
// Two-layer GCN, aggregate-then-GEMM (exact by linearity).
// R2: CSR gather (no atomics). R3: bf16 MFMA GEMM. R4: gather with wave-wide
// index prefetch + 4-wide independent row loads (MLP), fused small kernels.
//   agg_l[d,:]  = sum_{e: dst_l[e]=d} X_l[src_l[e],:] * rsqrt(deg_out_l[src])
//   out_l[d,:]  = relu( (agg_l @ W_l) * rsqrt(deg_in_l[d]) + b_l )
// NOTE: harness re-poison of 1.6 GB d_ws (~252 us) + d_in restore (~130 us)
// is inside the timed window — a ~380 us floor independent of our kernels.
// ---------------------------------------------------------------------------

#define D 256
#define N_DST0_CONST 40000   // fixed by setup_inputs(); not derivable from in_sizes

typedef __attribute__((ext_vector_type(8))) short s16x8;   // bf16 x8 (4 VGPRs)
typedef __attribute__((ext_vector_type(4))) short s16x4;   // bf16 x4
typedef __attribute__((ext_vector_type(4))) float f32x4;   // fp32 x4 acc

__device__ inline short f2bf(float f) {
    __hip_bfloat16 h = __float2bfloat16(f);
    return *reinterpret_cast<short*>(&h);
}

// ---------------- zero (ints) ----------------
__global__ void zero_i(int* __restrict__ p, int n) {
    int i = blockIdx.x * blockDim.x + threadIdx.x;
    int stride = gridDim.x * blockDim.x;
    for (; i < n; i += stride) p[i] = 0;
}

// ---------------- degree histograms, both layers in one launch ----------------
__global__ void count_deg_both(const int* __restrict__ src0, const int* __restrict__ dst0, int E0,
                               const int* __restrict__ src1, const int* __restrict__ dst1, int E1,
                               int* __restrict__ cs0, int* __restrict__ cd0,
                               int* __restrict__ cs1, int* __restrict__ cd1) {
    int e = blockIdx.x * blockDim.x + threadIdx.x;
    if (e < E0) {
        atomicAdd(&cs0[src0[e]], 1);
        atomicAdd(&cd0[dst0[e]], 1);
    } else if (e < E0 + E1) {
        int i = e - E0;
        atomicAdd(&cs1[src1[i]], 1);
        atomicAdd(&cd1[dst1[i]], 1);
    }
}

// ---------------- single-block exclusive scan (block 0: layer0, block 1: layer1) ----
__global__ __launch_bounds__(1024) void ex_scan_both(
    const int* __restrict__ cnt0, int* __restrict__ ptr0, int n0,
    const int* __restrict__ cnt1, int* __restrict__ ptr1, int n1) {
    const int* cnt = (blockIdx.x == 0) ? cnt0 : cnt1;
    int* ptr = (blockIdx.x == 0) ? ptr0 : ptr1;
    int n = (blockIdx.x == 0) ? n0 : n1;

    __shared__ int wsum[16];
    const int tid = threadIdx.x;
    const int chunk = (n + 1023) / 1024;
    const int begin = min(tid * chunk, n);
    const int end = min(begin + chunk, n);
    int local = 0;
    for (int i = begin; i < end; ++i) local += cnt[i];
    const int lane = tid & 63;
    const int wid = tid >> 6;
    int v = local;
    for (int off = 1; off < 64; off <<= 1) {
        int u = __shfl_up(v, off, 64);
        if (lane >= off) v += u;
    }
    if (lane == 63) wsum[wid] = v;
    __syncthreads();
    if (wid == 0 && lane < 16) {
        int w = wsum[lane];
        for (int off = 1; off < 16; off <<= 1) {
            int u = __shfl_up(w, off, 16);
            if (lane >= off) w += u;
        }
        wsum[lane] = w;
    }
    __syncthreads();
    int base = (wid > 0 ? wsum[wid - 1] : 0) + (v - local);
    int run = base;
    for (int i = begin; i < end; ++i) { ptr[i] = run; run += cnt[i]; }
}

// ---------------- CSR fill, both layers ----------------
// After this, ptr[d] == exclusive prefix of d+1: row d = [d? ptr[d-1]:0, ptr[d]).
__global__ void fill_csr_both(const int* __restrict__ src0, const int* __restrict__ dst0, int E0,
                              const int* __restrict__ src1, const int* __restrict__ dst1, int E1,
                              int* __restrict__ ptr0, int* __restrict__ es0,
                              int* __restrict__ ptr1, int* __restrict__ es1) {
    int e = blockIdx.x * blockDim.x + threadIdx.x;
    if (e < E0) {
        int pos = atomicAdd(&ptr0[dst0[e]], 1);
        es0[pos] = src0[e];
    } else if (e < E0 + E1) {
        int i = e - E0;
        int pos = atomicAdd(&ptr1[dst1[i]], 1);
        es1[pos] = src1[i];
    }
}

// ---------------- CSR gather aggregate -> bf16 (MLP version) ----------------
// blockDim = (64,4): one wave per dst row; lane covers 4 cols via float4.
// Wave-wide prefetch of indices+norms (contiguous in CSR), then 4 independent
// row loads in flight per iteration.
__global__ __launch_bounds__(256) void gather_agg_bf16(
    const float* __restrict__ X, const int* __restrict__ edge_src,
    const int* __restrict__ ptr, const int* __restrict__ cnt_src,
    short* __restrict__ agg, int nrows) {
    int d = blockIdx.x * 4 + threadIdx.y;
    if (d >= nrows) return;
    int beg = (d == 0) ? 0 : ptr[d - 1];
    int end = ptr[d];
    int deg = end - beg;
    int lane = threadIdx.x;

    // wave-wide prefetch (deg <= 64 fast path; Poisson(10) => max ~30)
    int s_l = 0;
    float rn_l = 0.f;
    if (lane < deg) {
        s_l = edge_src[beg + lane];
        rn_l = rsqrtf(fmaxf((float)cnt_src[s_l], 1.0f));
    }

    float4 acc = make_float4(0.f, 0.f, 0.f, 0.f);
    int nb = min(deg, 64);
    int j = 0;
    for (; j + 4 <= nb; j += 4) {
        int s0 = __shfl(s_l, j + 0), s1 = __shfl(s_l, j + 1);
        int s2 = __shfl(s_l, j + 2), s3 = __shfl(s_l, j + 3);
        float r0 = __shfl(rn_l, j + 0), r1 = __shfl(rn_l, j + 1);
        float r2 = __shfl(rn_l, j + 2), r3 = __shfl(rn_l, j + 3);
        float4 v0 = *(const float4*)(X + (size_t)s0 * D + lane * 4);
        float4 v1 = *(const float4*)(X + (size_t)s1 * D + lane * 4);
        float4 v2 = *(const float4*)(X + (size_t)s2 * D + lane * 4);
        float4 v3 = *(const float4*)(X + (size_t)s3 * D + lane * 4);
        acc.x += v0.x * r0 + v1.x * r1 + v2.x * r2 + v3.x * r3;
        acc.y += v0.y * r0 + v1.y * r1 + v2.y * r2 + v3.y * r3;
        acc.z += v0.z * r0 + v1.z * r1 + v2.z * r2 + v3.z * r3;
        acc.w += v0.w * r0 + v1.w * r1 + v2.w * r2 + v3.w * r3;
    }
    for (; j < nb; ++j) {
        int s = __shfl(s_l, j);
        float r = __shfl(rn_l, j);
        float4 v = *(const float4*)(X + (size_t)s * D + lane * 4);
        acc.x += v.x * r; acc.y += v.y * r; acc.z += v.z * r; acc.w += v.w * r;
    }
    // rare overflow path (deg > 64)
    for (int jj = beg + 64; jj < end; ++jj) {
        int s = edge_src[jj];
        float r = rsqrtf(fmaxf((float)cnt_src[s], 1.0f));
        float4 v = *(const float4*)(X + (size_t)s * D + lane * 4);
        acc.x += v.x * r; acc.y += v.y * r; acc.z += v.z * r; acc.w += v.w * r;
    }

    s16x4 o;
    o.x = f2bf(acc.x); o.y = f2bf(acc.y); o.z = f2bf(acc.z); o.w = f2bf(acc.w);
    *(s16x4*)(agg + (size_t)d * D + lane * 4) = o;
}

// ---------------- W (KxN fp32) -> W^T (NxK bf16), both weights ----------------
__global__ __launch_bounds__(256) void transpose_cast_w_both(
    const float* __restrict__ Wa, short* __restrict__ BTa,
    const float* __restrict__ Wb, short* __restrict__ BTb) {
    const float* W = (blockIdx.z == 0) ? Wa : Wb;
    short* BT = (blockIdx.z == 0) ? BTa : BTb;
    __shared__ float t[16][17];
    int k0 = blockIdx.x * 16, n0 = blockIdx.y * 16;
    t[threadIdx.y][threadIdx.x] = W[(size_t)(k0 + threadIdx.y) * D + n0 + threadIdx.x];
    __syncthreads();
    BT[(size_t)(n0 + threadIdx.y) * D + k0 + threadIdx.x] = f2bf(t[threadIdx.x][threadIdx.y]);
}

// ---------------- bf16 MFMA GEMM: out = relu(rsqrt(cnt[m])*(A@W) + bias) ----------------
// A [M][256] bf16, BT [256][256] bf16 (BT[n][k] = W[k][n]), out [M][256] fp32.
// 128x128 tile / block, 4 waves (2x2), each wave 64x64 via 4x4 16x16x32 MFMAs.
#define LDK 40   // padded LDS k-stride (bf16): 80B rows -> 2-way bank alias (free)

__global__ __launch_bounds__(256) void gemm_bf16_mfma(
    const short* __restrict__ A, const short* __restrict__ BT,
    const int* __restrict__ cnt_dst, const float* __restrict__ bias,
    float* __restrict__ out, int M) {
    __shared__ short As[128][LDK];
    __shared__ short Bs[128][LDK];

    const int tid = threadIdx.x;
    const int m0 = blockIdx.x * 128;
    const int n0 = blockIdx.y * 128;
    const int wave = tid >> 6;
    const int lane = tid & 63;
    const int l15 = lane & 15;
    const int quad = lane >> 4;
    const int mo = (wave & 1) * 64;
    const int no = (wave >> 1) * 64;

    f32x4 acc[4][4] = {};

    for (int k0 = 0; k0 < D; k0 += 32) {
#pragma unroll
        for (int i = 0; i < 2; ++i) {
            int idx = tid + i * 256;
            int row = idx >> 2;
            int kg = (idx & 3) * 8;
            int gm = m0 + row;
            s16x8 av = {};
            if (gm < M) av = *(const s16x8*)(A + (size_t)gm * D + k0 + kg);
            *(s16x8*)&As[row][kg] = av;
            s16x8 bv = *(const s16x8*)(BT + (size_t)(n0 + row) * D + k0 + kg);
            *(s16x8*)&Bs[row][kg] = bv;
        }
        __syncthreads();

        s16x8 af[4], bf[4];
#pragma unroll
        for (int mt = 0; mt < 4; ++mt)
            af[mt] = *(const s16x8*)&As[mo + mt * 16 + l15][quad * 8];
#pragma unroll
        for (int nt = 0; nt < 4; ++nt)
            bf[nt] = *(const s16x8*)&Bs[no + nt * 16 + l15][quad * 8];
#pragma unroll
        for (int mt = 0; mt < 4; ++mt)
#pragma unroll
            for (int nt = 0; nt < 4; ++nt)
                acc[mt][nt] = __builtin_amdgcn_mfma_f32_16x16x32_bf16(
                    af[mt], bf[nt], acc[mt][nt], 0, 0, 0);
        __syncthreads();
    }

    // epilogue: D row = quad*4 + r, col = l15 (per 16x16 tile)
#pragma unroll
    for (int mt = 0; mt < 4; ++mt) {
#pragma unroll
        for (int r = 0; r < 4; ++r) {
            int gm = m0 + mo + mt * 16 + quad * 4 + r;
            if (gm >= M) continue;
            float sc = rsqrtf(fmaxf((float)cnt_dst[gm], 1.0f));
#pragma unroll
            for (int nt = 0; nt < 4; ++nt) {
                int gn = n0 + no + nt * 16 + l15;
                float v = fmaxf(acc[mt][nt][r] * sc + bias[gn], 0.f);
                out[(size_t)gm * D + gn] = v;
            }
        }
    }
}

// ---------------------------------------------------------------------------

extern "C" void kernel_launch(void* const* d_in, const int* in_sizes, int n_in,
                              void* d_out, int out_size, void* d_ws, size_t ws_size,
                              hipStream_t stream) {
    const float* x    = (const float*)d_in[0];
    const int*   src0 = (const int*)d_in[1];
    const int*   dst0 = (const int*)d_in[2];
    const int*   src1 = (const int*)d_in[3];
    const int*   dst1 = (const int*)d_in[4];
    const float* W0   = (const float*)d_in[5];
    const float* b0   = (const float*)d_in[6];
    const float* W1   = (const float*)d_in[7];
    const float* b1   = (const float*)d_in[8];

    const int n_src0 = in_sizes[0] / D;      // 400000
    const int E0     = in_sizes[1];          // 400000
    const int E1     = in_sizes[3];          // 40000
    const int n_dst0 = N_DST0_CONST;         // 40000
    const int n_dst1 = out_size / D;         // 4000

    // ---- workspace layout ----
    char* base = (char*)d_ws;
    size_t off = 0;
    auto alloc = [&](size_t bytes) { void* p = base + off; off = (off + bytes + 63) & ~(size_t)63; return p; };

    int* icnt = (int*)alloc((size_t)(n_src0 + 2 * n_dst0 + n_dst1) * 4);
    int* icnt_src0 = icnt;
    int* icnt_dst0 = icnt + n_src0;
    int* icnt_src1 = icnt + n_src0 + n_dst0;
    int* icnt_dst1 = icnt + n_src0 + 2 * n_dst0;
    const int cnt_total = n_src0 + 2 * n_dst0 + n_dst1;    // 484000

    int* ptr0      = (int*)alloc((size_t)n_dst0 * 4);
    int* ptr1      = (int*)alloc((size_t)n_dst1 * 4);
    int* edge_src0 = (int*)alloc((size_t)E0 * 4);
    int* edge_src1 = (int*)alloc((size_t)E1 * 4);

    float* h0    = (float*)alloc((size_t)n_dst0 * D * 4);
    short* aggb0 = (short*)alloc((size_t)n_dst0 * D * 2);
    short* aggb1 = (short*)alloc((size_t)n_dst1 * D * 2);
    short* BT0   = (short*)alloc((size_t)D * D * 2);
    short* BT1   = (short*)alloc((size_t)D * D * 2);

    float* out = (float*)d_out;

    // 1. zero count region
    zero_i<<<512, 256, 0, stream>>>(icnt, cnt_total);

    // 2. degree histograms (both layers)
    count_deg_both<<<(E0 + E1 + 255) / 256, 256, 0, stream>>>(
        src0, dst0, E0, src1, dst1, E1, icnt_src0, icnt_dst0, icnt_src1, icnt_dst1);

    // 3. exclusive scans (both layers, one launch)
    ex_scan_both<<<2, 1024, 0, stream>>>(icnt_dst0, ptr0, n_dst0, icnt_dst1, ptr1, n_dst1);

    // 4. CSR fill (both layers)
    fill_csr_both<<<(E0 + E1 + 255) / 256, 256, 0, stream>>>(
        src0, dst0, E0, src1, dst1, E1, ptr0, edge_src0, ptr1, edge_src1);

    // 5. W -> W^T bf16 (both weights)
    {
        dim3 g(D / 16, D / 16, 2), b(16, 16);
        transpose_cast_w_both<<<g, b, 0, stream>>>(W0, BT0, W1, BT1);
    }

    // 6. layer0
    {
        dim3 blk(64, 4);
        gather_agg_bf16<<<(n_dst0 + 3) / 4, blk, 0, stream>>>(x, edge_src0, ptr0, icnt_src0, aggb0, n_dst0);
        dim3 grid((n_dst0 + 127) / 128, D / 128);
        gemm_bf16_mfma<<<grid, 256, 0, stream>>>(aggb0, BT0, icnt_dst0, b0, h0, n_dst0);
    }

    // 7. layer1 -> d_out
    {
        dim3 blk(64, 4);
        gather_agg_bf16<<<(n_dst1 + 3) / 4, blk, 0, stream>>>(h0, edge_src1, ptr1, icnt_src1, aggb1, n_dst1);
        dim3 grid((n_dst1 + 127) / 128, D / 128);
        gemm_bf16_mfma<<<grid, 256, 0, stream>>>(aggb1, BT1, icnt_dst1, b1, out, n_dst1);
    }
}